// Round 1
// baseline (1123.020 us; speedup 1.0000x reference)
//
#include <hip/hip_runtime.h>

#define NC 512   // N_CLUSTERS

// ---------------------------------------------------------------------------
// Stage 1: discretize — argmin over 512 centroids, first-occurrence ties.
// ---------------------------------------------------------------------------
__global__ __launch_bounds__(256) void k_discretize(
    const float* __restrict__ x, const float* __restrict__ cent, int* __restrict__ out)
{
    __shared__ float c[NC];
    int tid = threadIdx.x;
    for (int i = tid; i < NC; i += 256) c[i] = cent[i];
    __syncthreads();
    int id = blockIdx.x * 256 + tid;   // 128*32*32 = 131072 total, exact grid
    float px = x[id];
    float best = fabsf(px - c[0]);
    int bi = 0;
    for (int k = 1; k < NC; ++k) {
        float d = fabsf(px - c[k]);
        if (d < best) { best = d; bi = k; }   // strict < keeps first min (argmin)
    }
    out[id] = bi;
}

// ---------------------------------------------------------------------------
// Stage 2/3: symbolic conv (k=5, s=2) with _conv_reduce semantics.
// One thread = one (b, oy, ox, co) instance. Per-thread u8 histogram in LDS
// (layout bins[bin*64 + tid]); counting-sort pop-min replaces sort+insertion:
// pops are monotone non-decreasing and inserts (t2 > y) always land at/after
// the scan pointer, so a forward-only pointer is exact.
// ---------------------------------------------------------------------------
template<int K, int CIN, int CO, int IH, int IW, int OH, int OW>
__global__ __launch_bounds__(64) void k_conv(
    const int* __restrict__ in_sym,    // (B, IH, IW, CIN) channel-last
    const int* __restrict__ wsym,      // (N, CO)
    const int* __restrict__ conv_lut,  // (NC, NC)
    const int* __restrict__ add_lut,   // (NC, NC)
    const int* __restrict__ bias_lut,  // (NC, CO)
    const int* __restrict__ relu_lut,  // (NC,)
    int* __restrict__ out)             // (B, OH, OW, CO)
{
    constexpr int N = K * K * CIN;
    __shared__ unsigned char bins[NC * 64];   // 32 KB
    int tid = threadIdx.x;

    // cooperative zero (8192 dwords)
    unsigned int* bz = (unsigned int*)bins;
    for (int i = 0; i < 128; ++i) bz[i * 64 + tid] = 0u;
    __syncthreads();

    int id = blockIdx.x * 64 + tid;    // grids are exact multiples of 64
    int co = id % CO;
    int r  = id / CO;
    int ox = r % OW; r /= OW;
    int oy = r % OH;
    int b  = r / OH;

    // build histogram of g[n] = conv_lut[win_sym[n], wsym[n,co]]
    for (int n = 0; n < N; ++n) {
        int i   = n / (K * CIN);
        int rem = n % (K * CIN);
        int j   = rem / CIN;
        int c   = rem % CIN;
        int s = in_sym[((b * IH + (oy * 2 + i)) * IW + (ox * 2 + j)) * CIN + c];
        int w = wsym[n * CO + co];
        int g = conv_lut[s * NC + w];
        bins[g * 64 + tid]++;
    }

    // _conv_reduce: pop-min fold with conditional re-insertion
    int p = 0;
    while (bins[p * 64 + tid] == 0) ++p;
    bins[p * 64 + tid]--;
    int t = p;                                   // tmp = arr[0]
    for (int j = 1; j < N; ++j) {
        while (bins[p * 64 + tid] == 0) ++p;     // pop x = a[j]
        bins[p * 64 + tid]--;
        int x = p;
        int t2 = add_lut[x * NC + t];
        if (j < N - 2) {
            while (bins[p * 64 + tid] == 0) ++p; // peek y = a[j+1]
            int y = p;
            if (t2 > y) {                        // cond: swap t2 into pool, take y
                bins[p * 64 + tid]--;
                bins[t2 * 64 + tid]++;           // t2 > y >= p: never behind pointer
                t = y;
            } else {
                t = t2;
            }
        } else {
            t = t2;                              // last two steps: plain fold
        }
    }
    out[id] = relu_lut[bias_lut[t * CO + co]];
}

// ---------------------------------------------------------------------------
// Stage 4/5: symbolic FC with _fc_reduce (sorted ascending fold).
// u16 bins (counts can exceed 255 only in theory at K=400; be exact).
// PERM folds the (0,3,1,2)-transpose flatten of the (B,5,5,16) conv2 output.
// ---------------------------------------------------------------------------
template<int M, int K, bool PERM>
__global__ __launch_bounds__(64) void k_fc(
    const int* __restrict__ in_sym,
    const int* __restrict__ wsym,      // (M, K)
    const int* __restrict__ fc_lut,    // (NC, NC)
    const int* __restrict__ add_lut,   // (NC, NC)
    const int* __restrict__ bias_lut,  // (NC, M)
    const int* __restrict__ relu_lut,  // (NC,)
    int* __restrict__ out)             // (B, M)
{
    __shared__ unsigned short bins[NC * 64];  // 64 KB
    int tid = threadIdx.x;
    unsigned int* bz = (unsigned int*)bins;
    for (int i = 0; i < 256; ++i) bz[i * 64 + tid] = 0u;
    __syncthreads();

    int id = blockIdx.x * 64 + tid;
    int m = id % M;
    int b = id / M;

    for (int k = 0; k < K; ++k) {
        int xaddr;
        if (PERM) {
            // flat k = c*25 + (y*5+x); stored layout = b*400 + (y*5+x)*16 + c
            int c = k / 25, yx = k % 25;
            xaddr = b * 400 + yx * 16 + c;
        } else {
            xaddr = b * K + k;
        }
        int xs = in_sym[xaddr];
        int w  = wsym[m * K + k];
        int v  = fc_lut[xs * NC + w];
        bins[v * 64 + tid]++;
    }

    int p = 0;
    while (bins[p * 64 + tid] == 0) ++p;
    bins[p * 64 + tid]--;
    int t = p;                                  // t = arr[0]
    for (int s = 1; s < K; ++s) {               // fold ascending: t = add_lut[v, t]
        while (bins[p * 64 + tid] == 0) ++p;
        bins[p * 64 + tid]--;
        t = add_lut[p * NC + t];
    }
    out[id] = relu_lut[bias_lut[t * M + m]];
}

// ---------------------------------------------------------------------------
// Stage 6: head — feats = centroid[sym], logits = feats @ W^T + b, softmax.
// One thread per batch row (128 rows).
// ---------------------------------------------------------------------------
__global__ __launch_bounds__(64) void k_head(
    const int* __restrict__ f2_syms,   // (128, 84)
    const float* __restrict__ cent,    // (NC,)
    const float* __restrict__ w,       // (10, 84)
    const float* __restrict__ bias,    // (10,)
    float* __restrict__ out)           // (128, 10)
{
    int b = blockIdx.x * 64 + threadIdx.x;  // grid 2*64 = 128 exact
    float acc[10];
#pragma unroll
    for (int o = 0; o < 10; ++o) acc[o] = bias[o];
    for (int k = 0; k < 84; ++k) {
        float f = cent[f2_syms[b * 84 + k]];
#pragma unroll
        for (int o = 0; o < 10; ++o) acc[o] += f * w[o * 84 + k];
    }
    float mx = acc[0];
#pragma unroll
    for (int o = 1; o < 10; ++o) mx = fmaxf(mx, acc[o]);
    float s = 0.f;
#pragma unroll
    for (int o = 0; o < 10; ++o) { acc[o] = expf(acc[o] - mx); s += acc[o]; }
    float inv = 1.f / s;
#pragma unroll
    for (int o = 0; o < 10; ++o) out[b * 10 + o] = acc[o] * inv;
}

// ---------------------------------------------------------------------------
extern "C" void kernel_launch(void* const* d_in, const int* in_sizes, int n_in,
                              void* d_out, int out_size, void* d_ws, size_t ws_size,
                              hipStream_t stream)
{
    const float* x_bat  = (const float*)d_in[0];
    const float* cent   = (const float*)d_in[1];
    const int* conv_lut = (const int*)d_in[2];
    const int* fc_lut   = (const int*)d_in[3];
    const int* add_lut  = (const int*)d_in[4];
    const int* relu_lut = (const int*)d_in[5];
    const int* c1_bias  = (const int*)d_in[6];
    const int* c2_bias  = (const int*)d_in[7];
    const int* f1_bias  = (const int*)d_in[8];
    const int* f2_bias  = (const int*)d_in[9];
    const int* c1f      = (const int*)d_in[10];
    const int* c2f      = (const int*)d_in[11];
    const int* f1f      = (const int*)d_in[12];
    const int* f2f      = (const int*)d_in[13];
    const float* fc3_w  = (const float*)d_in[14];
    const float* fc3_b  = (const float*)d_in[15];
    float* out = (float*)d_out;

    char* ws = (char*)d_ws;
    int* sym0 = (int*)(ws);                                   // 128*32*32      = 512 KB
    int* c1o  = (int*)(ws + 524288);                          // 128*14*14*6    = 588 KB
    int* c2o  = (int*)(ws + 524288 + 602112);                 // 128*5*5*16     = 200 KB
    int* f1o  = (int*)(ws + 524288 + 602112 + 204800);        // 128*120        =  60 KB
    int* f2o  = (int*)(ws + 524288 + 602112 + 204800 + 61440);// 128*84         =  42 KB

    k_discretize<<<512, 256, 0, stream>>>(x_bat, cent, sym0);
    k_conv<5, 1, 6, 32, 32, 14, 14><<<150528 / 64, 64, 0, stream>>>(
        sym0, c1f, conv_lut, add_lut, c1_bias, relu_lut, c1o);
    k_conv<5, 6, 16, 14, 14, 5, 5><<<51200 / 64, 64, 0, stream>>>(
        c1o, c2f, conv_lut, add_lut, c2_bias, relu_lut, c2o);
    k_fc<120, 400, true><<<15360 / 64, 64, 0, stream>>>(
        c2o, f1f, fc_lut, add_lut, f1_bias, relu_lut, f1o);
    k_fc<84, 120, false><<<10752 / 64, 64, 0, stream>>>(
        f1o, f2f, fc_lut, add_lut, f2_bias, relu_lut, f2o);
    k_head<<<2, 64, 0, stream>>>(f2o, cent, fc3_w, fc3_b, out);
}

// Round 2
// 991.710 us; speedup vs baseline: 1.1324x; 1.1324x over previous
//
#include <hip/hip_runtime.h>

#define NC 512   // N_CLUSTERS

// ---------------------------------------------------------------------------
// Stage 1: discretize — argmin over 512 centroids, first-occurrence ties.
// ---------------------------------------------------------------------------
__global__ __launch_bounds__(256) void k_discretize(
    const float* __restrict__ x, const float* __restrict__ cent, int* __restrict__ out)
{
    __shared__ float c[NC];
    int tid = threadIdx.x;
    for (int i = tid; i < NC; i += 256) c[i] = cent[i];
    __syncthreads();
    int id = blockIdx.x * 256 + tid;   // 128*32*32 = 131072 total, exact grid
    float px = x[id];
    float best = fabsf(px - c[0]);
    int bi = 0;
    for (int k = 1; k < NC; ++k) {
        float d = fabsf(px - c[k]);
        if (d < best) { best = d; bi = k; }   // strict < keeps first min (argmin)
    }
    out[id] = bi;
}

// ---------------------------------------------------------------------------
// Register-window pop-min scanners. Per-lane 512-bin counting multiset in LDS;
// a 32-byte window is cached in 8 VGPRs with a nonzero mask so pops/peeks are
// pure VALU (ffbl + masked decrement). LDS is touched only on window advance
// (2x ds_read_b128) and on out-of-window inserts (byte RMW, DS is in-order
// per lane so the later window load sees it).
// ---------------------------------------------------------------------------
struct ScanU8 {                 // counts u8 (max multiset count <= 255)
    unsigned char* base;        // lane's 512-byte region
    uint32_t w[8];
    uint32_t mask;              // bit k set <=> byte k of window nonzero
    int chunk;                  // window index; bin = chunk*32 + k

    static __device__ inline uint32_t nz4(uint32_t x) {
        uint32_t y = (x & 0x7F7F7F7Fu) + 0x7F7F7F7Fu;
        y = (y | x) & 0x80808080u;          // high bit per nonzero byte
        return (y * 0x00204081u) >> 28;     // compact bits 7,15,23,31 -> 0..3
    }
    __device__ inline void init(unsigned char* b) { base = b; mask = 0; chunk = -1; }
    __device__ inline void load() {
        const uint4* p = (const uint4*)(base + chunk * 32);
        uint4 a = p[0], b = p[1];
        w[0]=a.x; w[1]=a.y; w[2]=a.z; w[3]=a.w;
        w[4]=b.x; w[5]=b.y; w[6]=b.z; w[7]=b.w;
        mask =  nz4(w[0])        | (nz4(w[1]) << 4)  | (nz4(w[2]) << 8)  | (nz4(w[3]) << 12)
             | (nz4(w[4]) << 16) | (nz4(w[5]) << 20) | (nz4(w[6]) << 24) | (nz4(w[7]) << 28);
    }
    __device__ inline void ensure() { while (mask == 0) { ++chunk; load(); } }
    __device__ inline int  peek()   { ensure(); return chunk * 32 + (int)__builtin_ctz(mask); }
    __device__ inline void consume_min() {           // precondition: mask != 0
        int k = (int)__builtin_ctz(mask);
        int dw = k >> 2, sh = (k & 3) << 3;
        uint32_t cnt = 0;
#pragma unroll
        for (int i = 0; i < 8; ++i) if (i == dw) { cnt = (w[i] >> sh) & 0xFFu; w[i] -= (1u << sh); }
        if (cnt == 1) mask &= ~(1u << k);
    }
    __device__ inline int pop() { int v = peek(); consume_min(); return v; }
    __device__ inline void insert(int v) {           // precondition: v > current min
        int rel = v - chunk * 32;
        if (rel < 32) {                              // rel >= 0 always (v > min in window)
            int dw = rel >> 2, sh = (rel & 3) << 3;
#pragma unroll
            for (int i = 0; i < 8; ++i) if (i == dw) w[i] += (1u << sh);
            mask |= (1u << rel);
        } else {
            base[v] = (unsigned char)(base[v] + 1);  // future window, visible at its load
        }
    }
};

struct ScanU16 {                // counts u16 (for K=400); window = 16 counts
    unsigned short* base;
    uint32_t w[8];
    uint32_t mask;              // 16-bit nonzero-halfword mask
    int chunk;                  // bin = chunk*16 + k

    static __device__ inline uint32_t nz2(uint32_t x) {
        uint32_t y = (x & 0x7FFF7FFFu) + 0x7FFF7FFFu;
        y = (y | x) & 0x80008000u;          // high bit per nonzero halfword
        return (y * 0x8001u) >> 30;         // bits 15,31 -> 0..1
    }
    __device__ inline void init(unsigned short* b) { base = b; mask = 0; chunk = -1; }
    __device__ inline void load() {
        const uint4* p = (const uint4*)((char*)base + chunk * 32);
        uint4 a = p[0], b = p[1];
        w[0]=a.x; w[1]=a.y; w[2]=a.z; w[3]=a.w;
        w[4]=b.x; w[5]=b.y; w[6]=b.z; w[7]=b.w;
        mask =  nz2(w[0])        | (nz2(w[1]) << 2)  | (nz2(w[2]) << 4)  | (nz2(w[3]) << 6)
             | (nz2(w[4]) << 8)  | (nz2(w[5]) << 10) | (nz2(w[6]) << 12) | (nz2(w[7]) << 14);
    }
    __device__ inline void ensure() { while (mask == 0) { ++chunk; load(); } }
    __device__ inline int pop() {
        ensure();
        int k = (int)__builtin_ctz(mask);
        int dw = k >> 1, sh = (k & 1) << 4;
        uint32_t cnt = 0;
#pragma unroll
        for (int i = 0; i < 8; ++i) if (i == dw) { cnt = (w[i] >> sh) & 0xFFFFu; w[i] -= (1u << sh); }
        if (cnt == 1) mask &= ~(1u << k);
        return chunk * 16 + k;
    }
};

// ---------------------------------------------------------------------------
// Stage 2/3: symbolic conv (k=5, s=2), _conv_reduce semantics (verified R1).
// One thread = one (b, oy, ox, co). Fold chain = add_lut L2 gather only.
// ---------------------------------------------------------------------------
template<int K, int CIN, int CO, int IH, int IW, int OH, int OW>
__global__ __launch_bounds__(64) void k_conv(
    const int* __restrict__ in_sym,    // (B, IH, IW, CIN)
    const int* __restrict__ wsym,      // (N, CO)
    const int* __restrict__ conv_lut,  // (NC, NC)
    const int* __restrict__ add_lut,   // (NC, NC)
    const int* __restrict__ bias_lut,  // (NC, CO)
    const int* __restrict__ relu_lut,  // (NC,)
    int* __restrict__ out)             // (B, OH, OW, CO)
{
    constexpr int N = K * K * CIN;
    __shared__ __align__(16) unsigned char bins[64 * NC];  // 32 KB, lane-contiguous
    int tid = threadIdx.x;

    uint32_t* bz = (uint32_t*)bins;
    for (int i = 0; i < 128; ++i) bz[i * 64 + tid] = 0u;   // conflict-free zero
    __syncthreads();

    int id = blockIdx.x * 64 + tid;    // grids are exact multiples of 64
    int co = id % CO;
    int r  = id / CO;
    int ox = r % OW; r /= OW;
    int oy = r % OH;
    int b  = r / OH;

    unsigned char* mybins = bins + tid * NC;
    for (int n = 0; n < N; ++n) {
        int i   = n / (K * CIN);
        int rem = n % (K * CIN);
        int j   = rem / CIN;
        int c   = rem % CIN;
        int s = in_sym[((b * IH + (oy * 2 + i)) * IW + (ox * 2 + j)) * CIN + c];
        int w = wsym[n * CO + co];
        int g = conv_lut[s * NC + w];
        mybins[g] = (unsigned char)(mybins[g] + 1);
    }

    ScanU8 sc; sc.init(mybins);
    int t = sc.pop();                            // tmp = arr[0]
    for (int j = 1; j < N; ++j) {
        int x = sc.pop();                        // a[j]
        int t2 = add_lut[x * NC + t];
        if (j < N - 2) {
            int y = sc.peek();                   // a[j+1]
            if (t2 > y) { sc.consume_min(); sc.insert(t2); t = y; }
            else t = t2;
        } else {
            t = t2;
        }
    }
    out[id] = relu_lut[bias_lut[t * CO + co]];
}

// ---------------------------------------------------------------------------
// Stage 4/5: symbolic FC, _fc_reduce = pure ascending pops (no inserts).
// U16=true for K=400 (counts can exceed 255).
// ---------------------------------------------------------------------------
template<int M, int K, bool PERM, bool U16>
__global__ __launch_bounds__(64) void k_fc(
    const int* __restrict__ in_sym,
    const int* __restrict__ wsym,      // (M, K)
    const int* __restrict__ fc_lut,    // (NC, NC)
    const int* __restrict__ add_lut,   // (NC, NC)
    const int* __restrict__ bias_lut,  // (NC, M)
    const int* __restrict__ relu_lut,  // (NC,)
    int* __restrict__ out)             // (B, M)
{
    constexpr int BPC = U16 ? 2 : 1;
    __shared__ __align__(16) unsigned char raw[64 * NC * BPC];  // 32 or 64 KB
    int tid = threadIdx.x;
    uint32_t* bz = (uint32_t*)raw;
    for (int i = 0; i < 128 * BPC; ++i) bz[i * 64 + tid] = 0u;
    __syncthreads();

    int id = blockIdx.x * 64 + tid;
    int m = id % M;
    int b = id / M;

    if (U16) {
        unsigned short* mybins = (unsigned short*)raw + tid * NC;
        for (int k = 0; k < K; ++k) {
            int xaddr;
            if (PERM) { int c = k / 25, yx = k % 25; xaddr = b * 400 + yx * 16 + c; }
            else      { xaddr = b * K + k; }
            int v = fc_lut[in_sym[xaddr] * NC + wsym[m * K + k]];
            mybins[v] = (unsigned short)(mybins[v] + 1);
        }
        ScanU16 sc; sc.init(mybins);
        int t = sc.pop();
        for (int s = 1; s < K; ++s) t = add_lut[sc.pop() * NC + t];
        out[id] = relu_lut[bias_lut[t * M + m]];
    } else {
        unsigned char* mybins = raw + tid * NC;
        for (int k = 0; k < K; ++k) {
            int xaddr;
            if (PERM) { int c = k / 25, yx = k % 25; xaddr = b * 400 + yx * 16 + c; }
            else      { xaddr = b * K + k; }
            int v = fc_lut[in_sym[xaddr] * NC + wsym[m * K + k]];
            mybins[v] = (unsigned char)(mybins[v] + 1);
        }
        ScanU8 sc; sc.init(mybins);
        int t = sc.pop();
        for (int s = 1; s < K; ++s) t = add_lut[sc.pop() * NC + t];
        out[id] = relu_lut[bias_lut[t * M + m]];
    }
}

// ---------------------------------------------------------------------------
// Stage 6: head — feats = centroid[sym], logits = feats @ W^T + b, softmax.
// ---------------------------------------------------------------------------
__global__ __launch_bounds__(64) void k_head(
    const int* __restrict__ f2_syms,   // (128, 84)
    const float* __restrict__ cent,    // (NC,)
    const float* __restrict__ w,       // (10, 84)
    const float* __restrict__ bias,    // (10,)
    float* __restrict__ out)           // (128, 10)
{
    int b = blockIdx.x * 64 + threadIdx.x;  // grid 2*64 = 128 exact
    float acc[10];
#pragma unroll
    for (int o = 0; o < 10; ++o) acc[o] = bias[o];
    for (int k = 0; k < 84; ++k) {
        float f = cent[f2_syms[b * 84 + k]];
#pragma unroll
        for (int o = 0; o < 10; ++o) acc[o] += f * w[o * 84 + k];
    }
    float mx = acc[0];
#pragma unroll
    for (int o = 1; o < 10; ++o) mx = fmaxf(mx, acc[o]);
    float s = 0.f;
#pragma unroll
    for (int o = 0; o < 10; ++o) { acc[o] = expf(acc[o] - mx); s += acc[o]; }
    float inv = 1.f / s;
#pragma unroll
    for (int o = 0; o < 10; ++o) out[b * 10 + o] = acc[o] * inv;
}

// ---------------------------------------------------------------------------
extern "C" void kernel_launch(void* const* d_in, const int* in_sizes, int n_in,
                              void* d_out, int out_size, void* d_ws, size_t ws_size,
                              hipStream_t stream)
{
    const float* x_bat  = (const float*)d_in[0];
    const float* cent   = (const float*)d_in[1];
    const int* conv_lut = (const int*)d_in[2];
    const int* fc_lut   = (const int*)d_in[3];
    const int* add_lut  = (const int*)d_in[4];
    const int* relu_lut = (const int*)d_in[5];
    const int* c1_bias  = (const int*)d_in[6];
    const int* c2_bias  = (const int*)d_in[7];
    const int* f1_bias  = (const int*)d_in[8];
    const int* f2_bias  = (const int*)d_in[9];
    const int* c1f      = (const int*)d_in[10];
    const int* c2f      = (const int*)d_in[11];
    const int* f1f      = (const int*)d_in[12];
    const int* f2f      = (const int*)d_in[13];
    const float* fc3_w  = (const float*)d_in[14];
    const float* fc3_b  = (const float*)d_in[15];
    float* out = (float*)d_out;

    char* ws = (char*)d_ws;
    int* sym0 = (int*)(ws);                                   // 128*32*32
    int* c1o  = (int*)(ws + 524288);                          // 128*14*14*6
    int* c2o  = (int*)(ws + 524288 + 602112);                 // 128*5*5*16
    int* f1o  = (int*)(ws + 524288 + 602112 + 204800);        // 128*120
    int* f2o  = (int*)(ws + 524288 + 602112 + 204800 + 61440);// 128*84

    k_discretize<<<512, 256, 0, stream>>>(x_bat, cent, sym0);
    k_conv<5, 1, 6, 32, 32, 14, 14><<<150528 / 64, 64, 0, stream>>>(
        sym0, c1f, conv_lut, add_lut, c1_bias, relu_lut, c1o);
    k_conv<5, 6, 16, 14, 14, 5, 5><<<51200 / 64, 64, 0, stream>>>(
        c1o, c2f, conv_lut, add_lut, c2_bias, relu_lut, c2o);
    k_fc<120, 400, true, true><<<15360 / 64, 64, 0, stream>>>(
        c2o, f1f, fc_lut, add_lut, f1_bias, relu_lut, f1o);
    k_fc<84, 120, false, false><<<10752 / 64, 64, 0, stream>>>(
        f1o, f2f, fc_lut, add_lut, f2_bias, relu_lut, f2o);
    k_head<<<2, 64, 0, stream>>>(f2o, cent, fc3_w, fc3_b, out);
}